// Round 8
// baseline (1404.079 us; speedup 1.0000x reference)
//
#include <hip/hip_runtime.h>
#include <hip/hip_bf16.h>
#include <math.h>

// ============================================================================
// RAWTextureDetector pipeline, fp32 end-to-end.
//   row-streamed fused conv1+conv2 -> conv3 -> multi-scale box-std maps ->
//   exact quantile (radix-histogram select) -> thresholds -> sigmoid mask
// R2: plane_std two-stage full-chip reduction (was 433us @1.3% occupancy).
// R3: hist2/hist3 LDS-merged sub-histograms (was 411us of contended atomics).
// R4: parallel histogram select (was 389us of serial L2-latency bin scans).
// R5: stdmap YB=4 sliding vertical windows + merged 3-scale scan (304->208us).
// R6 LESSON: don't trade FMA density for occupancy (4px/thread regressed).
// R7: conv1+conv2 fused via LDS f1 (f1 HBM round trip eliminated; 499us:
//     VALU 49%, 8 waves/CU, 7.6e7 LDS bank conflicts in f1 phase).
// R8: conv12 row-streaming rewrite: 3-row x/f1 rings + w2 in LDS (52.7KB ->
//     3 blocks/CU), per-row complete conv2 (acc[4] not acc[16][8]),
//     conflict-free lane mappings (2-way max), w1 hoisted to VGPRs.
// ============================================================================

// ---------------------------------------------------------------------------
// Row-streamed fused conv1+conv2. Block = 64 cols x 32 output rows.
// Per output row yo: stage x row yo+2 -> barrier -> compute f1 row yo+1
// (32ch x 68 cols into f1 ring) -> barrier -> conv2 row yo (complete over all
// 32 ci; 3 f1 ring rows present) -> store. Rings are mod-3; all overwrites
// are ordered by the two per-row barriers (verified slot-by-slot).
// f1-phase lanes: foc=t>>3 (fixed -> w1 in VGPRs), oc=t&7 (8-col strip).
// conv2-phase lanes: j=t>>4, cg=t&15 (4-px group; 16-way j broadcast on f1).
// ---------------------------------------------------------------------------
__global__ __launch_bounds__(256, 3) void conv12_k(
    const float* __restrict__ x,   // [nb, 4, 512, 512]
    const float* __restrict__ w1,  // [32, 4, 3, 3]
    const float* __restrict__ b1,  // [32]
    const float* __restrict__ w2,  // [16, 32, 3, 3]
    const float* __restrict__ b2,  // [16]
    float* __restrict__ f2)        // [nb, 16, 512, 512]
{
    __shared__ float xr[3][4][68];     // x ring: row slot = (Y+516)%3
    __shared__ float f1r[3][32][68];   // f1 ring: row slot = (Y1+516)%3
    __shared__ float w2s[32 * 16 * 12]; // [ci][j][12]: 9 weights + 3 pad

    const int t  = threadIdx.x;
    const int x0 = blockIdx.x * 64;
    const int y0 = blockIdx.y * 32;
    const int bb = blockIdx.z;
    const float* xb = x + (size_t)bb * 4 * 262144;

    // ---- stage w2 reshaped [ci][j][12] (pad slots read-but-unused) ----
    for (int i = t; i < 4608; i += 256) {
        int kk = i % 9;
        int r  = i / 9;           // ci*16 + j
        int j  = r & 15, ci = r >> 4;
        w2s[(ci * 16 + j) * 12 + kk] = w2[(j * 32 + ci) * 9 + kk];
    }

    // ---- fixed per-thread roles ----
    const int foc = t >> 3, oc = t & 7;     // f1 phase
    const int j2  = t >> 4, cg = t & 15;    // conv2 phase
    float wv[36];
#pragma unroll
    for (int k = 0; k < 36; ++k) wv[k] = w1[foc * 36 + k];
    const float f1b = b1[foc];
    const float b2v = b2[j2];

    auto stage_x = [&](int Y) {
        const int slot = (unsigned)(Y + 516) % 3u;
        for (int i = t; i < 272; i += 256) {
            int ci = i / 68, c = i - ci * 68;
            int X = x0 - 2 + c;
            float v = 0.f;
            if ((unsigned)Y < 512u && (unsigned)X < 512u)
                v = xb[ci * 262144 + Y * 512 + X];
            xr[slot][ci][c] = v;
        }
    };

    auto f1_row = [&](int Y1) {
        const int sw = (unsigned)(Y1 + 516) % 3u;
        int sk[3];
#pragma unroll
        for (int ky = 0; ky < 3; ++ky) sk[ky] = (unsigned)(Y1 - 1 + ky + 516) % 3u;
        const bool rowok = ((unsigned)Y1 < 512u);
        const int C0 = oc * 8;
        float v[8];
#pragma unroll
        for (int p = 0; p < 8; ++p) v[p] = f1b;
#pragma unroll
        for (int ci = 0; ci < 4; ++ci) {
#pragma unroll
            for (int ky = 0; ky < 3; ++ky) {
                const float* xp = &xr[sk[ky]][ci][C0];
                float4 A = *(const float4*)xp;
                float4 B = *(const float4*)(xp + 4);
                float2 Cq = *(const float2*)(xp + 8);
                float rr[10] = {A.x,A.y,A.z,A.w,B.x,B.y,B.z,B.w,Cq.x,Cq.y};
#pragma unroll
                for (int kx = 0; kx < 3; ++kx) {
                    float w = wv[ci * 9 + ky * 3 + kx];
#pragma unroll
                    for (int p = 0; p < 8; ++p)
                        v[p] = fmaf(rr[p + kx], w, v[p]);
                }
            }
        }
        float st[8];
#pragma unroll
        for (int p = 0; p < 8; ++p) {
            int X1 = x0 - 1 + C0 + p;
            float tv = v[p]; tv = tv > 0.f ? tv : 0.2f * tv;
            st[p] = (rowok && (unsigned)X1 < 512u) ? tv : 0.f;
        }
        *(float4*)&f1r[sw][foc][C0]     = make_float4(st[0],st[1],st[2],st[3]);
        *(float4*)&f1r[sw][foc][C0 + 4] = make_float4(st[4],st[5],st[6],st[7]);
        if (oc == 0) {
            // extra f1 cols 64,65 (66,67 zeroed; never read by conv2)
            float u0 = f1b, u1 = f1b;
#pragma unroll
            for (int ci = 0; ci < 4; ++ci) {
#pragma unroll
                for (int ky = 0; ky < 3; ++ky) {
                    const float* xp = &xr[sk[ky]][ci][64];
                    float4 A = *(const float4*)xp;   // x cols 64..67
                    float rr[4] = {A.x, A.y, A.z, A.w};
#pragma unroll
                    for (int kx = 0; kx < 3; ++kx) {
                        float w = wv[ci * 9 + ky * 3 + kx];
                        u0 = fmaf(rr[kx],     w, u0);
                        u1 = fmaf(rr[kx + 1], w, u1);
                    }
                }
            }
            u0 = u0 > 0.f ? u0 : 0.2f * u0;
            u1 = u1 > 0.f ? u1 : 0.2f * u1;
            int Xa = x0 + 63, Xb_ = x0 + 64;
            float sa = (rowok && (unsigned)Xa  < 512u) ? u0 : 0.f;
            float sb = (rowok && (unsigned)Xb_ < 512u) ? u1 : 0.f;
            *(float4*)&f1r[sw][foc][64] = make_float4(sa, sb, 0.f, 0.f);
        }
    };

    auto conv2_row = [&](int yo) {
        int sd[3];
#pragma unroll
        for (int dy = 0; dy < 3; ++dy) sd[dy] = (unsigned)(yo - 1 + dy + 516) % 3u;
        float a[4] = {0.f, 0.f, 0.f, 0.f};
        for (int ci = 0; ci < 32; ++ci) {
            const float* wp = &w2s[(ci * 16 + j2) * 12];
            float4 W0 = *(const float4*)wp;
            float4 W1 = *(const float4*)(wp + 4);
            float  W8 = wp[8];
            float wk[9] = {W0.x,W0.y,W0.z,W0.w,W1.x,W1.y,W1.z,W1.w,W8};
#pragma unroll
            for (int dy = 0; dy < 3; ++dy) {
                const float* fp = &f1r[sd[dy]][ci][cg * 4];
                float4 A = *(const float4*)fp;
                float2 B = *(const float2*)(fp + 4);
                float rr[6] = {A.x, A.y, A.z, A.w, B.x, B.y};
#pragma unroll
                for (int kx = 0; kx < 3; ++kx) {
                    float w = wk[dy * 3 + kx];
#pragma unroll
                    for (int p = 0; p < 4; ++p)
                        a[p] = fmaf(rr[p + kx], w, a[p]);
                }
            }
        }
        float o[4];
#pragma unroll
        for (int p = 0; p < 4; ++p) {
            float tv = a[p] + b2v;
            o[p] = tv > 0.f ? tv : 0.2f * tv;
        }
        *(float4*)(f2 + (((size_t)bb * 16 + j2) * 512 + yo) * 512 + x0 + cg * 4)
            = make_float4(o[0], o[1], o[2], o[3]);
    };

    // ---- prologue ----
    stage_x(y0 - 2); stage_x(y0 - 1); stage_x(y0);
    __syncthreads();
    f1_row(y0 - 1);
    __syncthreads();            // protect x slot (y0-2)%3 before restage
    stage_x(y0 + 1);
    __syncthreads();
    f1_row(y0);
    __syncthreads();

    // ---- main loop ----
    for (int yo = y0; yo < y0 + 32; ++yo) {
        stage_x(yo + 2);
        __syncthreads();        // x row visible; prev conv2 done before f1 write
        f1_row(yo + 1);
        __syncthreads();        // f1 row visible to conv2
        conv2_row(yo);
    }
}

// ---------------------------------------------------------------------------
// conv3: direct 3x3, zero pad. Tile 64x32, 8px/thread, COT=8 (R5 structure).
// ---------------------------------------------------------------------------
__global__ __launch_bounds__(256) void conv3_k(
    const float* __restrict__ in,   // [nb, 16, 512, 512]
    const float* __restrict__ wgt,  // [8, 16, 3, 3]
    const float* __restrict__ bias, // [8]
    float* __restrict__ out)        // [nb, 8, 512, 512]
{
    constexpr int TW = 64, TH = 32, SW = TW + 4;
    __shared__ float sl[(TH + 2) * SW];

    const int tx = threadIdx.x & 7;
    const int ty = threadIdx.x >> 3;
    const int x0 = blockIdx.x * TW;
    const int y0 = blockIdx.y * TH;
    const int bb = blockIdx.z;

    const float* inb = in + (size_t)bb * 16 * 262144;

    float acc[8][8];
#pragma unroll
    for (int j = 0; j < 8; ++j)
#pragma unroll
        for (int p = 0; p < 8; ++p) acc[j][p] = 0.f;

    for (int ci = 0; ci < 16; ++ci) {
        __syncthreads();
        const float* ip = inb + (size_t)ci * 262144;
        for (int idx = threadIdx.x; idx < (TH + 2) * (TW + 2); idx += 256) {
            int r  = idx / (TW + 2);
            int cc = idx - r * (TW + 2);
            int yy = y0 - 1 + r, xx = x0 - 1 + cc;
            float v = 0.f;
            if ((unsigned)yy < 512u && (unsigned)xx < 512u) v = ip[yy * 512 + xx];
            sl[r * SW + cc] = v;
        }
        __syncthreads();
        const float* wci = wgt + (size_t)ci * 9;
#pragma unroll
        for (int dy = 0; dy < 3; ++dy) {
            const float* rowp = &sl[(ty + dy) * SW + tx * 8];
            float4 a0 = *(const float4*)(rowp);
            float4 a1 = *(const float4*)(rowp + 4);
            float2 a2 = *(const float2*)(rowp + 8);
            float rr[10] = {a0.x, a0.y, a0.z, a0.w,
                            a1.x, a1.y, a1.z, a1.w, a2.x, a2.y};
#pragma unroll
            for (int j = 0; j < 8; ++j) {
#pragma unroll
                for (int dx = 0; dx < 3; ++dx) {
                    float w = wci[(size_t)j * 16 * 9 + dy * 3 + dx];
#pragma unroll
                    for (int p = 0; p < 8; ++p)
                        acc[j][p] = fmaf(rr[p + dx], w, acc[j][p]);
                }
            }
        }
    }

    const int y = y0 + ty;
#pragma unroll
    for (int j = 0; j < 8; ++j) {
        float b = bias[j];
        float* op = out + (((size_t)bb * 8 + j) * 512 + y) * 512 + x0 + tx * 8;
        float v[8];
#pragma unroll
        for (int p = 0; p < 8; ++p) v[p] = acc[j][p] + b;
        ((float4*)op)[0] = make_float4(v[0], v[1], v[2], v[3]);
        ((float4*)op)[1] = make_float4(v[4], v[5], v[6], v[7]);
    }
}

// ---------------------------------------------------------------------------
// Multi-scale std map + fusion (R5 sliding windows + R6 XCD swizzle).
// ---------------------------------------------------------------------------
__device__ __forceinline__ float2 f2add(float2 a, float2 b) {
    return make_float2(a.x + b.x, a.y + b.y);
}
__device__ __forceinline__ int mir(int v) {
    return v < 0 ? -v : (v > 511 ? 1022 - v : v);
}

#define YB 4

__global__ __launch_bounds__(256) void stdmap_k(
    const float* __restrict__ f,    // [nb, 8, 512, 512]
    const float* __restrict__ fw,   // fusion_w [3]
    const float* __restrict__ fbp,  // fusion_b [1]
    float* __restrict__ fused,      // [8, 512, 512] (global), offset by b0
    int b0)
{
    const int total = gridDim.x * gridDim.y;          // 128 * nb
    const int lin   = blockIdx.y * gridDim.x + blockIdx.x;
    const int task  = (lin & 7) * (total >> 3) + (lin >> 3);
    const int bb    = task >> 7;
    const int y0    = (task & 127) * YB;
    const int t    = threadIdx.x;
    const int lane = t & 63, wid = t >> 6;

    __shared__ float S[3][2][513];
    __shared__ float wtt[4][6];

    const int   RAD[3] = {5, 12, 24};
    const float INV[3] = {1.f/121.f, 1.f/625.f, 1.f/2401.f};

    float smacc[3][YB][2];
#pragma unroll
    for (int sc = 0; sc < 3; ++sc)
#pragma unroll
        for (int yy = 0; yy < YB; ++yy)
            { smacc[sc][yy][0] = 0.f; smacc[sc][yy][1] = 0.f; }

    for (int c = 0; c < 8; ++c) {
        const float* base = f + ((size_t)bb * 8 + c) * 512 * 512;

        float2 wf[3], wq[3];
        {
            float2 sf[3] = {{0.f,0.f},{0.f,0.f},{0.f,0.f}};
            float2 sq[3] = {{0.f,0.f},{0.f,0.f},{0.f,0.f}};
#pragma unroll
            for (int dy = -24; dy <= 24; ++dy) {
                int row = mir(y0 + dy);
                float2 v  = ((const float2*)(base + (size_t)row * 512))[t];
                float2 vq = make_float2(v.x * v.x, v.y * v.y);
                int ad = dy < 0 ? -dy : dy;
                int ring = ad <= 5 ? 0 : (ad <= 12 ? 1 : 2);
                sf[ring] = f2add(sf[ring], v);
                sq[ring] = f2add(sq[ring], vq);
            }
            wf[0] = sf[0];               wq[0] = sq[0];
            wf[1] = f2add(sf[1], wf[0]); wq[1] = f2add(sq[1], wq[0]);
            wf[2] = f2add(sf[2], wf[1]); wq[2] = f2add(sq[2], wq[1]);
        }

        for (int yy = 0; yy < YB; ++yy) {
            const int y = y0 + yy;
            if (yy > 0) {
#pragma unroll
                for (int sc = 0; sc < 3; ++sc) {
                    int ra = mir(y + RAD[sc]);
                    int rs = mir(y - 1 - RAD[sc]);
                    float2 va = ((const float2*)(base + (size_t)ra * 512))[t];
                    float2 vs = ((const float2*)(base + (size_t)rs * 512))[t];
                    wf[sc].x += va.x - vs.x;       wf[sc].y += va.y - vs.y;
                    wq[sc].x += va.x*va.x - vs.x*vs.x;
                    wq[sc].y += va.y*va.y - vs.y*vs.y;
                }
            }

            float pf[3], pq[3], incf[3], incq[3];
#pragma unroll
            for (int sc = 0; sc < 3; ++sc) {
                pf[sc] = wf[sc].x + wf[sc].y;
                pq[sc] = wq[sc].x + wq[sc].y;
                incf[sc] = pf[sc]; incq[sc] = pq[sc];
            }
#pragma unroll
            for (int off = 1; off < 64; off <<= 1) {
#pragma unroll
                for (int sc = 0; sc < 3; ++sc) {
                    float uf = __shfl_up(incf[sc], (unsigned)off, 64);
                    float uq = __shfl_up(incq[sc], (unsigned)off, 64);
                    if (lane >= off) { incf[sc] += uf; incq[sc] += uq; }
                }
            }
            if (lane == 63) {
#pragma unroll
                for (int sc = 0; sc < 3; ++sc) {
                    wtt[wid][sc]     = incf[sc];
                    wtt[wid][3 + sc] = incq[sc];
                }
            }
            __syncthreads();
            float wpf[3] = {0.f,0.f,0.f}, wpq[3] = {0.f,0.f,0.f};
#pragma unroll
            for (int w = 0; w < 4; ++w)
                if (w < wid)
#pragma unroll
                    for (int sc = 0; sc < 3; ++sc) {
                        wpf[sc] += wtt[w][sc];
                        wpq[sc] += wtt[w][3 + sc];
                    }
#pragma unroll
            for (int sc = 0; sc < 3; ++sc) {
                float exf = wpf[sc] + incf[sc] - pf[sc];
                float exq = wpq[sc] + incq[sc] - pq[sc];
                S[sc][0][2*t+1] = exf + wf[sc].x;
                S[sc][0][2*t+2] = exf + pf[sc];
                S[sc][1][2*t+1] = exq + wq[sc].x;
                S[sc][1][2*t+2] = exq + pq[sc];
            }
            if (t == 0)
#pragma unroll
                for (int sc = 0; sc < 3; ++sc)
                    { S[sc][0][0] = 0.f; S[sc][1][0] = 0.f; }
            __syncthreads();

#pragma unroll
            for (int sc = 0; sc < 3; ++sc) {
                const int r = RAD[sc];
                const float* Sf = S[sc][0];
                const float* Sq = S[sc][1];
#pragma unroll
                for (int slot = 0; slot < 2; ++slot) {
                    int xx = 2*t + slot;
                    int lo = xx - r, hi = xx + r;
                    int loc = lo < 0 ? 0 : lo;
                    int hic = hi > 511 ? 511 : hi;
                    float wfv = Sf[hic + 1] - Sf[loc];
                    float wqv = Sq[hic + 1] - Sq[loc];
                    if (lo < 0)   { wfv += Sf[r - xx + 1] - Sf[1];
                                    wqv += Sq[r - xx + 1] - Sq[1]; }
                    if (hi > 511) { wfv += Sf[511] - Sf[1022 - xx - r];
                                    wqv += Sq[511] - Sq[1022 - xx - r]; }
                    float m   = wfv * INV[sc];
                    float m2  = wqv * INV[sc];
                    float var = m2 - m * m;
                    var = var > 1e-6f ? var : 1e-6f;
                    smacc[sc][yy][slot] += sqrtf(var);
                }
            }
            __syncthreads();
        }
    }

    const float w0 = fw[0], w1 = fw[1], w2 = fw[2], b = fbp[0];
#pragma unroll
    for (int yy = 0; yy < YB; ++yy) {
        float o[2];
#pragma unroll
        for (int slot = 0; slot < 2; ++slot) {
            float m0 = powf(smacc[0][yy][slot] * 0.125f, 0.8f);
            float m1 = powf(smacc[1][yy][slot] * 0.125f, 0.8f);
            float m2 = powf(smacc[2][yy][slot] * 0.125f, 0.8f);
            float fv = w0 * m0 + w1 * m1 + w2 * m2 + b;
            o[slot] = fv > 0.f ? fv : 0.f;
        }
        ((float2*)(fused + ((size_t)(b0 + bb) * 512 + y0 + yy) * 512))[t] =
            make_float2(o[0], o[1]);
    }
}

// ---------------------------------------------------------------------------
// Per-(b,c) plane std of x, ddof=1. Two-stage deterministic reduction.
// ---------------------------------------------------------------------------
__global__ __launch_bounds__(256) void plane_std_part_k(
    const float* __restrict__ x, double* __restrict__ part)
{
    const int plane = blockIdx.x >> 5;
    const int blk   = blockIdx.x & 31;
    const float* p = x + (size_t)plane * 262144 + (size_t)blk * 8192;
    double s = 0.0, s2 = 0.0;
    for (int i = threadIdx.x; i < 2048; i += 256) {
        float4 v = ((const float4*)p)[i];
        s  += (double)v.x + (double)v.y + (double)v.z + (double)v.w;
        s2 += (double)v.x * v.x + (double)v.y * v.y
            + (double)v.z * v.z + (double)v.w * v.w;
    }
    __shared__ double ls[256], ls2[256];
    ls[threadIdx.x] = s; ls2[threadIdx.x] = s2;
    __syncthreads();
    for (int off = 128; off > 0; off >>= 1) {
        if (threadIdx.x < off) {
            ls[threadIdx.x]  += ls[threadIdx.x + off];
            ls2[threadIdx.x] += ls2[threadIdx.x + off];
        }
        __syncthreads();
    }
    if (threadIdx.x == 0) {
        part[2 * blockIdx.x]     = ls[0];
        part[2 * blockIdx.x + 1] = ls2[0];
    }
}

__global__ void plane_std_fin_k(const double* __restrict__ part,
                                float* __restrict__ stds)
{
    const int plane = threadIdx.x;
    if (plane >= 32) return;
    double s = 0.0, s2 = 0.0;
    for (int b = 0; b < 32; ++b) {
        s  += part[2 * (plane * 32 + b)];
        s2 += part[2 * (plane * 32 + b) + 1];
    }
    const double N = 262144.0;
    double var = (s2 - s * s / N) / (N - 1.0);
    stds[plane] = (float)sqrt(var > 0.0 ? var : 0.0);
}

// ---------------------------------------------------------------------------
// Exact quantile via 3-level radix histogram (12+12+8 bits).
// ---------------------------------------------------------------------------
__global__ __launch_bounds__(256) void hist1_k(
    const float* __restrict__ fused, unsigned* __restrict__ h)
{
    __shared__ unsigned lh[4096];
    for (int i = threadIdx.x; i < 4096; i += 256) lh[i] = 0u;
    __syncthreads();
    const int base = blockIdx.x * 2048;
    for (int i = threadIdx.x; i < 2048; i += 256) {
        unsigned bits = __float_as_uint(fused[base + i]);
        atomicAdd(&lh[bits >> 20], 1u);
    }
    __syncthreads();
    for (int i = threadIdx.x; i < 4096; i += 256) {
        unsigned c = lh[i];
        if (c) atomicAdd(&h[i], c);
    }
}

__global__ __launch_bounds__(256) void select_par_k(
    const unsigned* __restrict__ h, unsigned* __restrict__ pfx,
    unsigned* __restrict__ rem, int level)
{
    const int tt = blockIdx.x;
    const int t = threadIdx.x, lane = t & 63, wid = t >> 6;
    const unsigned targets[4] = {524287u, 524288u, 1572863u, 1572864u};
    const unsigned R = (level == 1) ? targets[tt] : rem[tt];
    const unsigned* hb = (level == 1) ? h : h + tt * 4096;

    unsigned loc[16], lsum = 0;
    const uint4* hv = (const uint4*)(hb + t * 16);
#pragma unroll
    for (int i = 0; i < 4; ++i) {
        uint4 v = hv[i];
        loc[4*i]=v.x; loc[4*i+1]=v.y; loc[4*i+2]=v.z; loc[4*i+3]=v.w;
        lsum += v.x + v.y + v.z + v.w;
    }
    __shared__ unsigned warr[4];
    __shared__ unsigned rbin, rrem;
    unsigned inc = lsum;
#pragma unroll
    for (int off = 1; off < 64; off <<= 1) {
        unsigned up = __shfl_up(inc, (unsigned)off, 64);
        if (lane >= off) inc += up;
    }
    if (lane == 63) warr[wid] = inc;
    __syncthreads();
    unsigned wpre = 0;
#pragma unroll
    for (int w = 0; w < 4; ++w) if (w < wid) wpre += warr[w];
    unsigned ex = wpre + inc - lsum;
    if (R >= ex && R < ex + lsum) {
        unsigned cum = ex;
#pragma unroll
        for (int i = 0; i < 16; ++i) {
            if (cum + loc[i] > R) { rbin = (unsigned)(t * 16 + i); rrem = R - cum; break; }
            cum += loc[i];
        }
    }
    __syncthreads();
    if (t == 0) {
        if (level == 1) { pfx[tt] = rbin << 20; rem[tt] = rrem; }
        else            { pfx[tt] |= rbin << 8; rem[tt] = rrem; }
    }
}

__global__ __launch_bounds__(256) void hist2_k(
    const float* __restrict__ fused, const unsigned* __restrict__ pfx,
    unsigned* __restrict__ h2)
{
    __shared__ unsigned lh[4 * 4096];
    for (int i = threadIdx.x; i < 4 * 4096; i += 256) lh[i] = 0u;
    unsigned p0 = pfx[0] >> 20, p1 = pfx[1] >> 20,
             p2 = pfx[2] >> 20, p3 = pfx[3] >> 20;
    __syncthreads();
    const int base = blockIdx.x * 2048;
    for (int i = threadIdx.x; i < 2048; i += 256) {
        unsigned bits = __float_as_uint(fused[base + i]);
        unsigned top = bits >> 20;
        unsigned mid = (bits >> 8) & 0xFFFu;
        if (top == p0) atomicAdd(&lh[0 * 4096 + mid], 1u);
        if (top == p1) atomicAdd(&lh[1 * 4096 + mid], 1u);
        if (top == p2) atomicAdd(&lh[2 * 4096 + mid], 1u);
        if (top == p3) atomicAdd(&lh[3 * 4096 + mid], 1u);
    }
    __syncthreads();
    for (int i = threadIdx.x; i < 4 * 4096; i += 256) {
        unsigned c = lh[i];
        if (c) atomicAdd(&h2[i], c);
    }
}

__global__ __launch_bounds__(256) void hist3_k(
    const float* __restrict__ fused, const unsigned* __restrict__ pfx,
    unsigned* __restrict__ h3)
{
    __shared__ unsigned lh[4 * 256];
    for (int i = threadIdx.x; i < 4 * 256; i += 256) lh[i] = 0u;
    unsigned p0 = pfx[0] >> 8, p1 = pfx[1] >> 8,
             p2 = pfx[2] >> 8, p3 = pfx[3] >> 8;
    __syncthreads();
    const int base = blockIdx.x * 2048;
    for (int i = threadIdx.x; i < 2048; i += 256) {
        unsigned bits = __float_as_uint(fused[base + i]);
        unsigned top = bits >> 8;
        unsigned low = bits & 0xFFu;
        if (top == p0) atomicAdd(&lh[0 * 256 + low], 1u);
        if (top == p1) atomicAdd(&lh[1 * 256 + low], 1u);
        if (top == p2) atomicAdd(&lh[2 * 256 + low], 1u);
        if (top == p3) atomicAdd(&lh[3 * 256 + low], 1u);
    }
    __syncthreads();
    for (int i = threadIdx.x; i < 4 * 256; i += 256) {
        unsigned c = lh[i];
        if (c) atomicAdd(&h3[i], c);
    }
}

__device__ __forceinline__ float clampf(float v, float lo, float hi) {
    return v < lo ? lo : (v > hi ? hi : v);
}

__global__ __launch_bounds__(256) void finalize_k(
    const unsigned* __restrict__ h3,
    const unsigned* __restrict__ pfx,
    const unsigned* __restrict__ rem,
    const float* __restrict__ stds,
    const float* __restrict__ cw,
    float* __restrict__ lu)
{
    const int tt = threadIdx.x >> 6, lane = threadIdx.x & 63;
    __shared__ float vals[4];

    {
        const unsigned R = rem[tt];
        const unsigned* h = h3 + tt * 256;
        uint4 v = ((const uint4*)h)[lane];
        unsigned loc[4] = {v.x, v.y, v.z, v.w};
        unsigned lsum = v.x + v.y + v.z + v.w;
        unsigned inc = lsum;
#pragma unroll
        for (int off = 1; off < 64; off <<= 1) {
            unsigned up = __shfl_up(inc, (unsigned)off, 64);
            if (lane >= off) inc += up;
        }
        unsigned ex = inc - lsum;
        if (R >= ex && R < ex + lsum) {
            unsigned cum = ex;
#pragma unroll
            for (int i = 0; i < 4; ++i) {
                if (cum + loc[i] > R) {
                    vals[tt] = __uint_as_float(pfx[tt] | (unsigned)(lane * 4 + i));
                    break;
                }
                cum += loc[i];
            }
        }
    }
    __syncthreads();
    if (threadIdx.x != 0) return;

    float q25 = vals[0] + 0.75f * (vals[1] - vals[0]);
    float q75 = vals[2] + 0.25f * (vals[3] - vals[2]);
    float iqr = q75 - q25;
    if (iqr < 1e-5f) iqr = 0.05f;
    float lo0 = q25 - 0.5f * iqr, up0 = q75 + 0.5f * iqr;

    float mx = cw[0];
    for (int c = 1; c < 4; ++c) mx = cw[c] > mx ? cw[c] : mx;
    float e[4], se = 0.f;
    for (int c = 0; c < 4; ++c) { e[c] = expf(cw[c] - mx); se += e[c]; }

    float l[32], u[32], mind = 1e30f;
    for (int p = 0; p < 32; ++p) {
        float sd = stds[p];
        int c = p & 3;
        float gf = clampf(sd * 5.f, 0.5f, 2.f);
        float cf = clampf(sd * (e[c] / se) * 2.f, 0.8f, 1.2f);
        l[p] = lo0 * gf * cf;
        u[p] = up0 * gf * cf;
        float d = fabsf(u[p] - l[p]);
        if (d < mind) mind = d;
    }
    bool deg = mind < 1e-5f;
    for (int p = 0; p < 32; ++p) {
        float L = l[p], U = u[p];
        if (deg) { float m = 0.5f * (L + U); L = m - 0.05f; U = m + 0.05f; }
        lu[p] = L; lu[32 + p] = U;
    }
}

__global__ __launch_bounds__(256) void mask_k(
    const float* __restrict__ fused, const float* __restrict__ lu,
    float* __restrict__ out)
{
    const int b = blockIdx.y;
    const int i = blockIdx.x * 256 + threadIdx.x;
    float fv = fused[(size_t)b * 262144 + i];
    float s = 0.f;
#pragma unroll
    for (int c = 0; c < 4; ++c) {
        float L = lu[b * 4 + c], U = lu[32 + b * 4 + c];
        float d = U - L; d = d > 1e-5f ? d : 1e-5f;
        float n = (fv - L) / d;
        n = n < 0.f ? 0.f : (n > 1.f ? 1.f : n);
        s += 1.f / (1.f + expf(3.f - 6.f * n));
    }
    out[(size_t)b * 262144 + i] = 0.25f * s;
}

// ---------------------------------------------------------------------------
extern "C" void kernel_launch(void* const* d_in, const int* in_sizes, int n_in,
                              void* d_out, int out_size, void* d_ws, size_t ws_size,
                              hipStream_t stream)
{
    const float* x   = (const float*)d_in[0];
    const float* c1w = (const float*)d_in[1];
    const float* c1b = (const float*)d_in[2];
    const float* c2w = (const float*)d_in[3];
    const float* c2b = (const float*)d_in[4];
    const float* c3w = (const float*)d_in[5];
    const float* c3b = (const float*)d_in[6];
    const float* fw  = (const float*)d_in[7];
    const float* fb  = (const float*)d_in[8];
    const float* cwt = (const float*)d_in[9];
    float* out = (float*)d_out;
    char* ws = (char*)d_ws;

    const size_t PLANE = 512 * 512;

    // ws layout: fused | stds | lu | pfx | rem | h1|h2|h3 | partials | chunk
    float* fused = (float*)ws;
    size_t off = 8 * PLANE * sizeof(float);
    float* stds = (float*)(ws + off); off += 32 * 4;
    float* lu   = (float*)(ws + off); off += 64 * 4;
    off = (off + 255) & ~(size_t)255;
    unsigned* pfx = (unsigned*)(ws + off); off += 16;
    unsigned* rem = (unsigned*)(ws + off); off += 16;
    off = (off + 255) & ~(size_t)255;
    unsigned* h1 = (unsigned*)(ws + off); off += 4096 * 4;
    unsigned* h2 = (unsigned*)(ws + off); off += 4 * 4096 * 4;
    unsigned* h3 = (unsigned*)(ws + off); off += 4 * 256 * 4;
    off = (off + 255) & ~(size_t)255;
    double* part = (double*)(ws + off); off += 1024 * 2 * sizeof(double);
    off = (off + 1023) & ~(size_t)1023;

    // chunk buffers: f2(16ch) + f(8ch) per batch = 24 planes (f1 is LDS-only)
    const size_t perb = 24 * PLANE * sizeof(float);
    int nb = 8;
    while (nb > 1 && off + (size_t)nb * perb > ws_size) nb >>= 1;
    float* f2  = (float*)(ws + off);
    float* fch = f2 + (size_t)nb * 16 * PLANE;

    hipLaunchKernelGGL(plane_std_part_k, dim3(1024), dim3(256), 0, stream, x, part);
    hipLaunchKernelGGL(plane_std_fin_k,  dim3(1),    dim3(64),  0, stream, part, stds);

    for (int b0 = 0; b0 < 8; b0 += nb) {
        const float* xc = x + (size_t)b0 * 4 * PLANE;
        hipLaunchKernelGGL(conv12_k, dim3(8, 16, nb), dim3(256), 0, stream,
                           xc, c1w, c1b, c2w, c2b, f2);
        hipLaunchKernelGGL(conv3_k,  dim3(8, 16, nb), dim3(256), 0, stream,
                           f2, c3w, c3b, fch);
        hipLaunchKernelGGL(stdmap_k, dim3(512 / YB, nb), dim3(256), 0, stream,
                           fch, fw, fb, fused, b0);
    }

    hipMemsetAsync(h1, 0, (4096 + 4 * 4096 + 4 * 256) * 4, stream);
    hipLaunchKernelGGL(hist1_k,     dim3(1024), dim3(256), 0, stream, fused, h1);
    hipLaunchKernelGGL(select_par_k, dim3(4),   dim3(256), 0, stream, h1, pfx, rem, 1);
    hipLaunchKernelGGL(hist2_k,     dim3(1024), dim3(256), 0, stream, fused, pfx, h2);
    hipLaunchKernelGGL(select_par_k, dim3(4),   dim3(256), 0, stream, h2, pfx, rem, 2);
    hipLaunchKernelGGL(hist3_k,     dim3(1024), dim3(256), 0, stream, fused, pfx, h3);
    hipLaunchKernelGGL(finalize_k,  dim3(1),    dim3(256), 0, stream,
                       h3, pfx, rem, stds, cwt, lu);
    hipLaunchKernelGGL(mask_k, dim3(1024, 8), dim3(256), 0, stream, fused, lu, out);
}

// Round 9
// 1095.092 us; speedup vs baseline: 1.2822x; 1.2822x over previous
//
#include <hip/hip_runtime.h>
#include <hip/hip_bf16.h>
#include <math.h>

// ============================================================================
// RAWTextureDetector pipeline, fp32 end-to-end.
//   fused conv1+conv2 (tile, f1 in LDS) -> conv3 -> multi-scale box-std maps
//   -> exact quantile (radix-histogram select) -> thresholds -> sigmoid mask
// R2: plane_std two-stage full-chip reduction (was 433us @1.3% occupancy).
// R3: hist2/hist3 LDS-merged sub-histograms (was 411us of contended atomics).
// R4: parallel histogram select (was 389us of serial L2-latency bin scans).
// R5: stdmap YB=4 sliding vertical windows + merged 3-scale scan (304->208us).
// R6 LESSON: don't trade FMA density for occupancy (4px/thread regressed).
// R7: conv1+conv2 fused via LDS f1 (499us; 7.6e7 LDS bank-conflict cycles).
// R8 LESSON: row-streaming regressed (830us, 1.5e8 conflicts): wave64 b128
//     has a hardware floor of 8 lanes/bank-quad - remapping can't beat it,
//     and per-row barriers at 8 waves/CU are exposed.
// R9: revert conv12 to R7 tile structure + read x once per (item,ci) for all
//     4 f1 channels (f1-phase LDS read traffic / 4; was re-read per channel).
// ============================================================================

// ---------------------------------------------------------------------------
// Fused conv1+conv2. Block = 64x32 f2-output tile, 256 threads, each owns
// 8 px x 16 f2-channels (acc[16][8]). x halo (68x36, 4ch) staged to LDS once;
// f1 computed group-of-4-channels at a time into LDS (all 4 channels per
// x-read), then consumed. LDS: xs 38.3KB + f1s 36.1KB = 76KB -> 2 blocks/CU.
// ---------------------------------------------------------------------------
__global__ __launch_bounds__(256, 2) void conv12_k(
    const float* __restrict__ x,   // [nb, 4, 512, 512]
    const float* __restrict__ w1,  // [32, 4, 3, 3]
    const float* __restrict__ b1,  // [32]
    const float* __restrict__ w2,  // [16, 32, 3, 3]
    const float* __restrict__ b2,  // [16]
    float* __restrict__ f2)        // [nb, 16, 512, 512]
{
    // xs: [4][36][68]  (x at rows y0-2..y0+33, cols x0-2..x0+65, zero-padded)
    // f1s: [4][34][68] (f1 group at rows y0-1..y0+32, cols x0-1..x0+66(pad))
    __shared__ float xs[4 * 36 * 68];    // 9792 floats
    __shared__ float f1s[4 * 34 * 68];   // 9248 floats

    const int t  = threadIdx.x;
    const int tx = t & 7;      // 8 x-groups of 8 px
    const int ty = t >> 3;     // 32 rows
    const int x0 = blockIdx.x * 64;
    const int y0 = blockIdx.y * 32;
    const int bb = blockIdx.z;
    const float* xb = x + (size_t)bb * 4 * 262144;

    // ---- stage x halo (zero-padded) ----
    for (int i = t; i < 9792; i += 256) {
        int ci  = i / 2448;              // 36*68
        int rem = i - ci * 2448;
        int r   = rem / 68;
        int c   = rem - r * 68;
        int Y = y0 - 2 + r, X = x0 - 2 + c;
        float v = 0.f;
        if ((unsigned)Y < 512u && (unsigned)X < 512u)
            v = xb[ci * 262144 + Y * 512 + X];
        xs[i] = v;
    }

    float acc[16][8];
#pragma unroll
    for (int j = 0; j < 16; ++j)
#pragma unroll
        for (int p = 0; p < 8; ++p) acc[j][p] = 0.f;

    for (int g = 0; g < 8; ++g) {
        __syncthreads();   // g=0: xs staged; g>0: prior f1s reads done

        // ---- compute f1 group g (channels g*4..g*4+3): x read ONCE per ci,
        //      all 4 output channels accumulated together ----
        {
            const int g4 = g * 4;
            for (int it = t; it < 578; it += 256) {   // 34 rows x 17 quads
                int r  = it / 17;
                int q  = it - r * 17;
                int c0 = q * 4;
                int Y1 = y0 - 1 + r;
                float v[4][4];   // [fc][px]
#pragma unroll
                for (int fc = 0; fc < 4; ++fc) {
                    float b = b1[g4 + fc];
                    v[fc][0] = b; v[fc][1] = b; v[fc][2] = b; v[fc][3] = b;
                }
#pragma unroll
                for (int ci = 0; ci < 4; ++ci) {
#pragma unroll
                    for (int ky = 0; ky < 3; ++ky) {
                        const float* xr = &xs[ci * 2448 + (r + ky) * 68 + c0];
                        float4 a  = *(const float4*)xr;
                        float2 bl = *(const float2*)(xr + 4);
                        float rr[6] = {a.x, a.y, a.z, a.w, bl.x, bl.y};
#pragma unroll
                        for (int fc = 0; fc < 4; ++fc) {
#pragma unroll
                            for (int kx = 0; kx < 3; ++kx) {
                                float w = w1[(g4 + fc) * 36 + ci * 9 + ky * 3 + kx];
#pragma unroll
                                for (int p = 0; p < 4; ++p)
                                    v[fc][p] = fmaf(rr[p + kx], w, v[fc][p]);
                            }
                        }
                    }
                }
                // lrelu + zero at f1-global-OOB (conv2 zero-padding) + pad cols
                bool rowok = ((unsigned)Y1 < 512u);
#pragma unroll
                for (int fc = 0; fc < 4; ++fc) {
                    float st[4];
#pragma unroll
                    for (int p = 0; p < 4; ++p) {
                        int X1 = x0 - 1 + c0 + p;
                        bool ok = rowok && ((unsigned)X1 < 512u) && (c0 + p <= 65);
                        float tv = v[fc][p];
                        tv = tv > 0.f ? tv : 0.2f * tv;
                        st[p] = ok ? tv : 0.f;
                    }
                    *(float4*)&f1s[fc * 2312 + r * 68 + c0] =
                        make_float4(st[0], st[1], st[2], st[3]);
                }
            }
        }
        __syncthreads();

        // ---- conv2 accumulate from this f1 group ----
#pragma unroll
        for (int fc = 0; fc < 4; ++fc) {
            const int ci = g * 4 + fc;
#pragma unroll
            for (int dy = 0; dy < 3; ++dy) {
                const float* rowp = &f1s[fc * 2312 + (ty + dy) * 68 + tx * 8];
                float4 a0 = *(const float4*)(rowp);
                float4 a1 = *(const float4*)(rowp + 4);
                float2 a2 = *(const float2*)(rowp + 8);
                float rr[10] = {a0.x, a0.y, a0.z, a0.w,
                                a1.x, a1.y, a1.z, a1.w, a2.x, a2.y};
#pragma unroll
                for (int j = 0; j < 16; ++j) {
#pragma unroll
                    for (int dx = 0; dx < 3; ++dx) {
                        float w = w2[(j * 32 + ci) * 9 + dy * 3 + dx];
#pragma unroll
                        for (int p = 0; p < 8; ++p)
                            acc[j][p] = fmaf(rr[p + dx], w, acc[j][p]);
                    }
                }
            }
        }
    }

    // ---- epilogue: bias + lrelu, write f2 ----
    const int y = y0 + ty;
#pragma unroll
    for (int j = 0; j < 16; ++j) {
        float b = b2[j];
        float* op = f2 + (((size_t)bb * 16 + j) * 512 + y) * 512 + x0 + tx * 8;
        float v[8];
#pragma unroll
        for (int p = 0; p < 8; ++p) {
            float tv = acc[j][p] + b;
            v[p] = tv > 0.f ? tv : 0.2f * tv;
        }
        ((float4*)op)[0] = make_float4(v[0], v[1], v[2], v[3]);
        ((float4*)op)[1] = make_float4(v[4], v[5], v[6], v[7]);
    }
}

// ---------------------------------------------------------------------------
// conv3: direct 3x3, zero pad. Tile 64x32, 8px/thread, COT=8 (R5 structure).
// ---------------------------------------------------------------------------
__global__ __launch_bounds__(256) void conv3_k(
    const float* __restrict__ in,   // [nb, 16, 512, 512]
    const float* __restrict__ wgt,  // [8, 16, 3, 3]
    const float* __restrict__ bias, // [8]
    float* __restrict__ out)        // [nb, 8, 512, 512]
{
    constexpr int TW = 64, TH = 32, SW = TW + 4;
    __shared__ float sl[(TH + 2) * SW];

    const int tx = threadIdx.x & 7;
    const int ty = threadIdx.x >> 3;
    const int x0 = blockIdx.x * TW;
    const int y0 = blockIdx.y * TH;
    const int bb = blockIdx.z;

    const float* inb = in + (size_t)bb * 16 * 262144;

    float acc[8][8];
#pragma unroll
    for (int j = 0; j < 8; ++j)
#pragma unroll
        for (int p = 0; p < 8; ++p) acc[j][p] = 0.f;

    for (int ci = 0; ci < 16; ++ci) {
        __syncthreads();
        const float* ip = inb + (size_t)ci * 262144;
        for (int idx = threadIdx.x; idx < (TH + 2) * (TW + 2); idx += 256) {
            int r  = idx / (TW + 2);
            int cc = idx - r * (TW + 2);
            int yy = y0 - 1 + r, xx = x0 - 1 + cc;
            float v = 0.f;
            if ((unsigned)yy < 512u && (unsigned)xx < 512u) v = ip[yy * 512 + xx];
            sl[r * SW + cc] = v;
        }
        __syncthreads();
        const float* wci = wgt + (size_t)ci * 9;
#pragma unroll
        for (int dy = 0; dy < 3; ++dy) {
            const float* rowp = &sl[(ty + dy) * SW + tx * 8];
            float4 a0 = *(const float4*)(rowp);
            float4 a1 = *(const float4*)(rowp + 4);
            float2 a2 = *(const float2*)(rowp + 8);
            float rr[10] = {a0.x, a0.y, a0.z, a0.w,
                            a1.x, a1.y, a1.z, a1.w, a2.x, a2.y};
#pragma unroll
            for (int j = 0; j < 8; ++j) {
#pragma unroll
                for (int dx = 0; dx < 3; ++dx) {
                    float w = wci[(size_t)j * 16 * 9 + dy * 3 + dx];
#pragma unroll
                    for (int p = 0; p < 8; ++p)
                        acc[j][p] = fmaf(rr[p + dx], w, acc[j][p]);
                }
            }
        }
    }

    const int y = y0 + ty;
#pragma unroll
    for (int j = 0; j < 8; ++j) {
        float b = bias[j];
        float* op = out + (((size_t)bb * 8 + j) * 512 + y) * 512 + x0 + tx * 8;
        float v[8];
#pragma unroll
        for (int p = 0; p < 8; ++p) v[p] = acc[j][p] + b;
        ((float4*)op)[0] = make_float4(v[0], v[1], v[2], v[3]);
        ((float4*)op)[1] = make_float4(v[4], v[5], v[6], v[7]);
    }
}

// ---------------------------------------------------------------------------
// Multi-scale std map + fusion (R5 sliding windows + R6 XCD swizzle).
// ---------------------------------------------------------------------------
__device__ __forceinline__ float2 f2add(float2 a, float2 b) {
    return make_float2(a.x + b.x, a.y + b.y);
}
__device__ __forceinline__ int mir(int v) {
    return v < 0 ? -v : (v > 511 ? 1022 - v : v);
}

#define YB 4

__global__ __launch_bounds__(256) void stdmap_k(
    const float* __restrict__ f,    // [nb, 8, 512, 512]
    const float* __restrict__ fw,   // fusion_w [3]
    const float* __restrict__ fbp,  // fusion_b [1]
    float* __restrict__ fused,      // [8, 512, 512] (global), offset by b0
    int b0)
{
    const int total = gridDim.x * gridDim.y;          // 128 * nb
    const int lin   = blockIdx.y * gridDim.x + blockIdx.x;
    const int task  = (lin & 7) * (total >> 3) + (lin >> 3);
    const int bb    = task >> 7;
    const int y0    = (task & 127) * YB;
    const int t    = threadIdx.x;
    const int lane = t & 63, wid = t >> 6;

    __shared__ float S[3][2][513];
    __shared__ float wtt[4][6];

    const int   RAD[3] = {5, 12, 24};
    const float INV[3] = {1.f/121.f, 1.f/625.f, 1.f/2401.f};

    float smacc[3][YB][2];
#pragma unroll
    for (int sc = 0; sc < 3; ++sc)
#pragma unroll
        for (int yy = 0; yy < YB; ++yy)
            { smacc[sc][yy][0] = 0.f; smacc[sc][yy][1] = 0.f; }

    for (int c = 0; c < 8; ++c) {
        const float* base = f + ((size_t)bb * 8 + c) * 512 * 512;

        float2 wf[3], wq[3];
        {
            float2 sf[3] = {{0.f,0.f},{0.f,0.f},{0.f,0.f}};
            float2 sq[3] = {{0.f,0.f},{0.f,0.f},{0.f,0.f}};
#pragma unroll
            for (int dy = -24; dy <= 24; ++dy) {
                int row = mir(y0 + dy);
                float2 v  = ((const float2*)(base + (size_t)row * 512))[t];
                float2 vq = make_float2(v.x * v.x, v.y * v.y);
                int ad = dy < 0 ? -dy : dy;
                int ring = ad <= 5 ? 0 : (ad <= 12 ? 1 : 2);
                sf[ring] = f2add(sf[ring], v);
                sq[ring] = f2add(sq[ring], vq);
            }
            wf[0] = sf[0];               wq[0] = sq[0];
            wf[1] = f2add(sf[1], wf[0]); wq[1] = f2add(sq[1], wq[0]);
            wf[2] = f2add(sf[2], wf[1]); wq[2] = f2add(sq[2], wq[1]);
        }

        for (int yy = 0; yy < YB; ++yy) {
            const int y = y0 + yy;
            if (yy > 0) {
#pragma unroll
                for (int sc = 0; sc < 3; ++sc) {
                    int ra = mir(y + RAD[sc]);
                    int rs = mir(y - 1 - RAD[sc]);
                    float2 va = ((const float2*)(base + (size_t)ra * 512))[t];
                    float2 vs = ((const float2*)(base + (size_t)rs * 512))[t];
                    wf[sc].x += va.x - vs.x;       wf[sc].y += va.y - vs.y;
                    wq[sc].x += va.x*va.x - vs.x*vs.x;
                    wq[sc].y += va.y*va.y - vs.y*vs.y;
                }
            }

            float pf[3], pq[3], incf[3], incq[3];
#pragma unroll
            for (int sc = 0; sc < 3; ++sc) {
                pf[sc] = wf[sc].x + wf[sc].y;
                pq[sc] = wq[sc].x + wq[sc].y;
                incf[sc] = pf[sc]; incq[sc] = pq[sc];
            }
#pragma unroll
            for (int off = 1; off < 64; off <<= 1) {
#pragma unroll
                for (int sc = 0; sc < 3; ++sc) {
                    float uf = __shfl_up(incf[sc], (unsigned)off, 64);
                    float uq = __shfl_up(incq[sc], (unsigned)off, 64);
                    if (lane >= off) { incf[sc] += uf; incq[sc] += uq; }
                }
            }
            if (lane == 63) {
#pragma unroll
                for (int sc = 0; sc < 3; ++sc) {
                    wtt[wid][sc]     = incf[sc];
                    wtt[wid][3 + sc] = incq[sc];
                }
            }
            __syncthreads();
            float wpf[3] = {0.f,0.f,0.f}, wpq[3] = {0.f,0.f,0.f};
#pragma unroll
            for (int w = 0; w < 4; ++w)
                if (w < wid)
#pragma unroll
                    for (int sc = 0; sc < 3; ++sc) {
                        wpf[sc] += wtt[w][sc];
                        wpq[sc] += wtt[w][3 + sc];
                    }
#pragma unroll
            for (int sc = 0; sc < 3; ++sc) {
                float exf = wpf[sc] + incf[sc] - pf[sc];
                float exq = wpq[sc] + incq[sc] - pq[sc];
                S[sc][0][2*t+1] = exf + wf[sc].x;
                S[sc][0][2*t+2] = exf + pf[sc];
                S[sc][1][2*t+1] = exq + wq[sc].x;
                S[sc][1][2*t+2] = exq + pq[sc];
            }
            if (t == 0)
#pragma unroll
                for (int sc = 0; sc < 3; ++sc)
                    { S[sc][0][0] = 0.f; S[sc][1][0] = 0.f; }
            __syncthreads();

#pragma unroll
            for (int sc = 0; sc < 3; ++sc) {
                const int r = RAD[sc];
                const float* Sf = S[sc][0];
                const float* Sq = S[sc][1];
#pragma unroll
                for (int slot = 0; slot < 2; ++slot) {
                    int xx = 2*t + slot;
                    int lo = xx - r, hi = xx + r;
                    int loc = lo < 0 ? 0 : lo;
                    int hic = hi > 511 ? 511 : hi;
                    float wfv = Sf[hic + 1] - Sf[loc];
                    float wqv = Sq[hic + 1] - Sq[loc];
                    if (lo < 0)   { wfv += Sf[r - xx + 1] - Sf[1];
                                    wqv += Sq[r - xx + 1] - Sq[1]; }
                    if (hi > 511) { wfv += Sf[511] - Sf[1022 - xx - r];
                                    wqv += Sq[511] - Sq[1022 - xx - r]; }
                    float m   = wfv * INV[sc];
                    float m2  = wqv * INV[sc];
                    float var = m2 - m * m;
                    var = var > 1e-6f ? var : 1e-6f;
                    smacc[sc][yy][slot] += sqrtf(var);
                }
            }
            __syncthreads();
        }
    }

    const float w0 = fw[0], w1 = fw[1], w2 = fw[2], b = fbp[0];
#pragma unroll
    for (int yy = 0; yy < YB; ++yy) {
        float o[2];
#pragma unroll
        for (int slot = 0; slot < 2; ++slot) {
            float m0 = powf(smacc[0][yy][slot] * 0.125f, 0.8f);
            float m1 = powf(smacc[1][yy][slot] * 0.125f, 0.8f);
            float m2 = powf(smacc[2][yy][slot] * 0.125f, 0.8f);
            float fv = w0 * m0 + w1 * m1 + w2 * m2 + b;
            o[slot] = fv > 0.f ? fv : 0.f;
        }
        ((float2*)(fused + ((size_t)(b0 + bb) * 512 + y0 + yy) * 512))[t] =
            make_float2(o[0], o[1]);
    }
}

// ---------------------------------------------------------------------------
// Per-(b,c) plane std of x, ddof=1. Two-stage deterministic reduction.
// ---------------------------------------------------------------------------
__global__ __launch_bounds__(256) void plane_std_part_k(
    const float* __restrict__ x, double* __restrict__ part)
{
    const int plane = blockIdx.x >> 5;
    const int blk   = blockIdx.x & 31;
    const float* p = x + (size_t)plane * 262144 + (size_t)blk * 8192;
    double s = 0.0, s2 = 0.0;
    for (int i = threadIdx.x; i < 2048; i += 256) {
        float4 v = ((const float4*)p)[i];
        s  += (double)v.x + (double)v.y + (double)v.z + (double)v.w;
        s2 += (double)v.x * v.x + (double)v.y * v.y
            + (double)v.z * v.z + (double)v.w * v.w;
    }
    __shared__ double ls[256], ls2[256];
    ls[threadIdx.x] = s; ls2[threadIdx.x] = s2;
    __syncthreads();
    for (int off = 128; off > 0; off >>= 1) {
        if (threadIdx.x < off) {
            ls[threadIdx.x]  += ls[threadIdx.x + off];
            ls2[threadIdx.x] += ls2[threadIdx.x + off];
        }
        __syncthreads();
    }
    if (threadIdx.x == 0) {
        part[2 * blockIdx.x]     = ls[0];
        part[2 * blockIdx.x + 1] = ls2[0];
    }
}

__global__ void plane_std_fin_k(const double* __restrict__ part,
                                float* __restrict__ stds)
{
    const int plane = threadIdx.x;
    if (plane >= 32) return;
    double s = 0.0, s2 = 0.0;
    for (int b = 0; b < 32; ++b) {
        s  += part[2 * (plane * 32 + b)];
        s2 += part[2 * (plane * 32 + b) + 1];
    }
    const double N = 262144.0;
    double var = (s2 - s * s / N) / (N - 1.0);
    stds[plane] = (float)sqrt(var > 0.0 ? var : 0.0);
}

// ---------------------------------------------------------------------------
// Exact quantile via 3-level radix histogram (12+12+8 bits).
// ---------------------------------------------------------------------------
__global__ __launch_bounds__(256) void hist1_k(
    const float* __restrict__ fused, unsigned* __restrict__ h)
{
    __shared__ unsigned lh[4096];
    for (int i = threadIdx.x; i < 4096; i += 256) lh[i] = 0u;
    __syncthreads();
    const int base = blockIdx.x * 2048;
    for (int i = threadIdx.x; i < 2048; i += 256) {
        unsigned bits = __float_as_uint(fused[base + i]);
        atomicAdd(&lh[bits >> 20], 1u);
    }
    __syncthreads();
    for (int i = threadIdx.x; i < 4096; i += 256) {
        unsigned c = lh[i];
        if (c) atomicAdd(&h[i], c);
    }
}

__global__ __launch_bounds__(256) void select_par_k(
    const unsigned* __restrict__ h, unsigned* __restrict__ pfx,
    unsigned* __restrict__ rem, int level)
{
    const int tt = blockIdx.x;
    const int t = threadIdx.x, lane = t & 63, wid = t >> 6;
    const unsigned targets[4] = {524287u, 524288u, 1572863u, 1572864u};
    const unsigned R = (level == 1) ? targets[tt] : rem[tt];
    const unsigned* hb = (level == 1) ? h : h + tt * 4096;

    unsigned loc[16], lsum = 0;
    const uint4* hv = (const uint4*)(hb + t * 16);
#pragma unroll
    for (int i = 0; i < 4; ++i) {
        uint4 v = hv[i];
        loc[4*i]=v.x; loc[4*i+1]=v.y; loc[4*i+2]=v.z; loc[4*i+3]=v.w;
        lsum += v.x + v.y + v.z + v.w;
    }
    __shared__ unsigned warr[4];
    __shared__ unsigned rbin, rrem;
    unsigned inc = lsum;
#pragma unroll
    for (int off = 1; off < 64; off <<= 1) {
        unsigned up = __shfl_up(inc, (unsigned)off, 64);
        if (lane >= off) inc += up;
    }
    if (lane == 63) warr[wid] = inc;
    __syncthreads();
    unsigned wpre = 0;
#pragma unroll
    for (int w = 0; w < 4; ++w) if (w < wid) wpre += warr[w];
    unsigned ex = wpre + inc - lsum;
    if (R >= ex && R < ex + lsum) {
        unsigned cum = ex;
#pragma unroll
        for (int i = 0; i < 16; ++i) {
            if (cum + loc[i] > R) { rbin = (unsigned)(t * 16 + i); rrem = R - cum; break; }
            cum += loc[i];
        }
    }
    __syncthreads();
    if (t == 0) {
        if (level == 1) { pfx[tt] = rbin << 20; rem[tt] = rrem; }
        else            { pfx[tt] |= rbin << 8; rem[tt] = rrem; }
    }
}

__global__ __launch_bounds__(256) void hist2_k(
    const float* __restrict__ fused, const unsigned* __restrict__ pfx,
    unsigned* __restrict__ h2)
{
    __shared__ unsigned lh[4 * 4096];
    for (int i = threadIdx.x; i < 4 * 4096; i += 256) lh[i] = 0u;
    unsigned p0 = pfx[0] >> 20, p1 = pfx[1] >> 20,
             p2 = pfx[2] >> 20, p3 = pfx[3] >> 20;
    __syncthreads();
    const int base = blockIdx.x * 2048;
    for (int i = threadIdx.x; i < 2048; i += 256) {
        unsigned bits = __float_as_uint(fused[base + i]);
        unsigned top = bits >> 20;
        unsigned mid = (bits >> 8) & 0xFFFu;
        if (top == p0) atomicAdd(&lh[0 * 4096 + mid], 1u);
        if (top == p1) atomicAdd(&lh[1 * 4096 + mid], 1u);
        if (top == p2) atomicAdd(&lh[2 * 4096 + mid], 1u);
        if (top == p3) atomicAdd(&lh[3 * 4096 + mid], 1u);
    }
    __syncthreads();
    for (int i = threadIdx.x; i < 4 * 4096; i += 256) {
        unsigned c = lh[i];
        if (c) atomicAdd(&h2[i], c);
    }
}

__global__ __launch_bounds__(256) void hist3_k(
    const float* __restrict__ fused, const unsigned* __restrict__ pfx,
    unsigned* __restrict__ h3)
{
    __shared__ unsigned lh[4 * 256];
    for (int i = threadIdx.x; i < 4 * 256; i += 256) lh[i] = 0u;
    unsigned p0 = pfx[0] >> 8, p1 = pfx[1] >> 8,
             p2 = pfx[2] >> 8, p3 = pfx[3] >> 8;
    __syncthreads();
    const int base = blockIdx.x * 2048;
    for (int i = threadIdx.x; i < 2048; i += 256) {
        unsigned bits = __float_as_uint(fused[base + i]);
        unsigned top = bits >> 8;
        unsigned low = bits & 0xFFu;
        if (top == p0) atomicAdd(&lh[0 * 256 + low], 1u);
        if (top == p1) atomicAdd(&lh[1 * 256 + low], 1u);
        if (top == p2) atomicAdd(&lh[2 * 256 + low], 1u);
        if (top == p3) atomicAdd(&lh[3 * 256 + low], 1u);
    }
    __syncthreads();
    for (int i = threadIdx.x; i < 4 * 256; i += 256) {
        unsigned c = lh[i];
        if (c) atomicAdd(&h3[i], c);
    }
}

__device__ __forceinline__ float clampf(float v, float lo, float hi) {
    return v < lo ? lo : (v > hi ? hi : v);
}

__global__ __launch_bounds__(256) void finalize_k(
    const unsigned* __restrict__ h3,
    const unsigned* __restrict__ pfx,
    const unsigned* __restrict__ rem,
    const float* __restrict__ stds,
    const float* __restrict__ cw,
    float* __restrict__ lu)
{
    const int tt = threadIdx.x >> 6, lane = threadIdx.x & 63;
    __shared__ float vals[4];

    {
        const unsigned R = rem[tt];
        const unsigned* h = h3 + tt * 256;
        uint4 v = ((const uint4*)h)[lane];
        unsigned loc[4] = {v.x, v.y, v.z, v.w};
        unsigned lsum = v.x + v.y + v.z + v.w;
        unsigned inc = lsum;
#pragma unroll
        for (int off = 1; off < 64; off <<= 1) {
            unsigned up = __shfl_up(inc, (unsigned)off, 64);
            if (lane >= off) inc += up;
        }
        unsigned ex = inc - lsum;
        if (R >= ex && R < ex + lsum) {
            unsigned cum = ex;
#pragma unroll
            for (int i = 0; i < 4; ++i) {
                if (cum + loc[i] > R) {
                    vals[tt] = __uint_as_float(pfx[tt] | (unsigned)(lane * 4 + i));
                    break;
                }
                cum += loc[i];
            }
        }
    }
    __syncthreads();
    if (threadIdx.x != 0) return;

    float q25 = vals[0] + 0.75f * (vals[1] - vals[0]);
    float q75 = vals[2] + 0.25f * (vals[3] - vals[2]);
    float iqr = q75 - q25;
    if (iqr < 1e-5f) iqr = 0.05f;
    float lo0 = q25 - 0.5f * iqr, up0 = q75 + 0.5f * iqr;

    float mx = cw[0];
    for (int c = 1; c < 4; ++c) mx = cw[c] > mx ? cw[c] : mx;
    float e[4], se = 0.f;
    for (int c = 0; c < 4; ++c) { e[c] = expf(cw[c] - mx); se += e[c]; }

    float l[32], u[32], mind = 1e30f;
    for (int p = 0; p < 32; ++p) {
        float sd = stds[p];
        int c = p & 3;
        float gf = clampf(sd * 5.f, 0.5f, 2.f);
        float cf = clampf(sd * (e[c] / se) * 2.f, 0.8f, 1.2f);
        l[p] = lo0 * gf * cf;
        u[p] = up0 * gf * cf;
        float d = fabsf(u[p] - l[p]);
        if (d < mind) mind = d;
    }
    bool deg = mind < 1e-5f;
    for (int p = 0; p < 32; ++p) {
        float L = l[p], U = u[p];
        if (deg) { float m = 0.5f * (L + U); L = m - 0.05f; U = m + 0.05f; }
        lu[p] = L; lu[32 + p] = U;
    }
}

__global__ __launch_bounds__(256) void mask_k(
    const float* __restrict__ fused, const float* __restrict__ lu,
    float* __restrict__ out)
{
    const int b = blockIdx.y;
    const int i = blockIdx.x * 256 + threadIdx.x;
    float fv = fused[(size_t)b * 262144 + i];
    float s = 0.f;
#pragma unroll
    for (int c = 0; c < 4; ++c) {
        float L = lu[b * 4 + c], U = lu[32 + b * 4 + c];
        float d = U - L; d = d > 1e-5f ? d : 1e-5f;
        float n = (fv - L) / d;
        n = n < 0.f ? 0.f : (n > 1.f ? 1.f : n);
        s += 1.f / (1.f + expf(3.f - 6.f * n));
    }
    out[(size_t)b * 262144 + i] = 0.25f * s;
}

// ---------------------------------------------------------------------------
extern "C" void kernel_launch(void* const* d_in, const int* in_sizes, int n_in,
                              void* d_out, int out_size, void* d_ws, size_t ws_size,
                              hipStream_t stream)
{
    const float* x   = (const float*)d_in[0];
    const float* c1w = (const float*)d_in[1];
    const float* c1b = (const float*)d_in[2];
    const float* c2w = (const float*)d_in[3];
    const float* c2b = (const float*)d_in[4];
    const float* c3w = (const float*)d_in[5];
    const float* c3b = (const float*)d_in[6];
    const float* fw  = (const float*)d_in[7];
    const float* fb  = (const float*)d_in[8];
    const float* cwt = (const float*)d_in[9];
    float* out = (float*)d_out;
    char* ws = (char*)d_ws;

    const size_t PLANE = 512 * 512;

    // ws layout: fused | stds | lu | pfx | rem | h1|h2|h3 | partials | chunk
    float* fused = (float*)ws;
    size_t off = 8 * PLANE * sizeof(float);
    float* stds = (float*)(ws + off); off += 32 * 4;
    float* lu   = (float*)(ws + off); off += 64 * 4;
    off = (off + 255) & ~(size_t)255;
    unsigned* pfx = (unsigned*)(ws + off); off += 16;
    unsigned* rem = (unsigned*)(ws + off); off += 16;
    off = (off + 255) & ~(size_t)255;
    unsigned* h1 = (unsigned*)(ws + off); off += 4096 * 4;
    unsigned* h2 = (unsigned*)(ws + off); off += 4 * 4096 * 4;
    unsigned* h3 = (unsigned*)(ws + off); off += 4 * 256 * 4;
    off = (off + 255) & ~(size_t)255;
    double* part = (double*)(ws + off); off += 1024 * 2 * sizeof(double);
    off = (off + 1023) & ~(size_t)1023;

    // chunk buffers: f2(16ch) + f(8ch) per batch = 24 planes (f1 is LDS-only)
    const size_t perb = 24 * PLANE * sizeof(float);
    int nb = 8;
    while (nb > 1 && off + (size_t)nb * perb > ws_size) nb >>= 1;
    float* f2  = (float*)(ws + off);
    float* fch = f2 + (size_t)nb * 16 * PLANE;

    hipLaunchKernelGGL(plane_std_part_k, dim3(1024), dim3(256), 0, stream, x, part);
    hipLaunchKernelGGL(plane_std_fin_k,  dim3(1),    dim3(64),  0, stream, part, stds);

    for (int b0 = 0; b0 < 8; b0 += nb) {
        const float* xc = x + (size_t)b0 * 4 * PLANE;
        hipLaunchKernelGGL(conv12_k, dim3(8, 16, nb), dim3(256), 0, stream,
                           xc, c1w, c1b, c2w, c2b, f2);
        hipLaunchKernelGGL(conv3_k,  dim3(8, 16, nb), dim3(256), 0, stream,
                           f2, c3w, c3b, fch);
        hipLaunchKernelGGL(stdmap_k, dim3(512 / YB, nb), dim3(256), 0, stream,
                           fch, fw, fb, fused, b0);
    }

    hipMemsetAsync(h1, 0, (4096 + 4 * 4096 + 4 * 256) * 4, stream);
    hipLaunchKernelGGL(hist1_k,     dim3(1024), dim3(256), 0, stream, fused, h1);
    hipLaunchKernelGGL(select_par_k, dim3(4),   dim3(256), 0, stream, h1, pfx, rem, 1);
    hipLaunchKernelGGL(hist2_k,     dim3(1024), dim3(256), 0, stream, fused, pfx, h2);
    hipLaunchKernelGGL(select_par_k, dim3(4),   dim3(256), 0, stream, h2, pfx, rem, 2);
    hipLaunchKernelGGL(hist3_k,     dim3(1024), dim3(256), 0, stream, fused, pfx, h3);
    hipLaunchKernelGGL(finalize_k,  dim3(1),    dim3(256), 0, stream,
                       h3, pfx, rem, stds, cwt, lu);
    hipLaunchKernelGGL(mask_k, dim3(1024, 8), dim3(256), 0, stream, fused, lu, out);
}